// Round 5
// baseline (91.681 us; speedup 1.0000x reference)
//
#include <hip/hip_runtime.h>
#include <hip/hip_bf16.h>
#include <math.h>

#define BH   32
#define NH   16
#define MM   1024
#define DD   64
#define PP   1024
#define SPAN 1024

typedef unsigned short ushort_t;
typedef __attribute__((ext_vector_type(8))) short  short8;
typedef __attribute__((ext_vector_type(4))) float  f32x4;

#define MFMA(a,b,c) __builtin_amdgcn_mfma_f32_16x16x32_bf16(a,b,c,0,0,0)

// ws layout (bytes):
//   [0, 8 MB)              K/V fragment blobs (ushort), chunk blob (h,c) = 16384 ushorts
//   [8 MB, 8 MB+256 KB)    per-row [m_pers, s_pers] float pairs (32768 rows)
//   [8.25 MB, 12.25 MB)    oraw: unscaled PV accumulator, f16, [row][64]
#define WS_MS_OFF   (8388608ull)
#define WS_ORAW_OFF (8650752ull)
#define WS_NEED     (12845056ull)

__device__ __forceinline__ ushort_t f2bf(float x) {
    __hip_bfloat16 b = __float2bfloat16(x);
    return __builtin_bit_cast(unsigned short, b);
}
__device__ __forceinline__ float bf2f(ushort_t u) {
    __hip_bfloat16 b = __builtin_bit_cast(__hip_bfloat16, u);
    return __bfloat162float(b);
}

// ---------------- pre-kernel: split-bf16 K/V fragment packing ----------------
// blocks [0,512): key -> K frag blobs: slot(l,e) = key[h][ks*32+(l>>4)*8+e][c*64+pb*16+(l&15)]
// blocks [512,1024): val -> V frag blobs: slot(l,e) = val[h][c*64+ks2*32+(l>>4)*4+(e&3)+16*(e>>2)][db*16+(l&15)]
__launch_bounds__(256)
__global__ void pm_pre(const float* __restrict__ key,
                       const float* __restrict__ val,
                       ushort_t* __restrict__ wsKV)
{
    int bi = blockIdx.x, t = threadIdx.x;
    if (bi < 512) {
        int id = bi * 256 + t;
        int l  = id & 63;
        int ks = (id >> 6) & 1;
        int pb = (id >> 7) & 3;
        int c  = (id >> 9) & 15;
        int h  = id >> 13;
        int p     = c * 64 + pb * 16 + (l & 15);
        int dbase = ks * 32 + (l >> 4) * 8;
        size_t fo = (size_t)(h * 16 + c) * 16384 + (size_t)(pb * 2 + ks) * 1024 + (size_t)l * 8;
#pragma unroll
        for (int e = 0; e < 8; ++e) {
            float x = key[(size_t)(h * 64 + dbase + e) * PP + p];
            ushort_t hh = f2bf(x);
            wsKV[fo + e]       = hh;
            wsKV[fo + 512 + e] = f2bf(x - bf2f(hh));
        }
    } else {
        int id = (bi - 512) * 256 + t;
        int l   = id & 63;
        int db  = (id >> 6) & 3;
        int ks2 = (id >> 8) & 1;
        int c   = (id >> 9) & 15;
        int h   = id >> 13;
        int d = db * 16 + (l & 15);
        size_t fo = (size_t)(h * 16 + c) * 16384 + 8192 + (size_t)(ks2 * 4 + db) * 1024 + (size_t)l * 8;
#pragma unroll
        for (int e = 0; e < 8; ++e) {
            int p = c * 64 + ks2 * 32 + ((l >> 4) * 4) + (e & 3) + 16 * (e >> 2);
            float x = val[(size_t)(h * PP + p) * DD + d];
            ushort_t hh = f2bf(x);
            wsKV[fo + e]       = hh;
            wsKV[fo + 512 + e] = f2bf(x - bf2f(hh));
        }
    }
}

// ---------------- main kernel: pure flash over persistent keys (no attn access) ----------------
__launch_bounds__(256)
__global__ void pm_main(const float* __restrict__ q,
                        const ushort_t* __restrict__ wsKV,
                        float* __restrict__ ws_ms,
                        _Float16* __restrict__ oraw)
{
    __shared__ ushort_t kvbuf[2][16384];   // 2 x 32 KB double buffer

    const int t  = threadIdx.x;
    const int w  = t >> 6;
    const int l  = t & 63;
    const int bi = blockIdx.x;
    const int bh   = bi & 31;     // bi%8 == bh%8 -> same-h blocks share an XCD's L2
    const int tile = bi >> 5;
    const int h  = bh & (NH - 1);
    const int hi = l >> 4;
    const int lo = l & 15;
    const int m0 = tile * 64 + w * 16;

    // Q fragments from global fp32 (B-operand of S^T mfma), split hi/lo bf16
    // slot(l,e) = Q[m0+(l&15)][ks*32 + (l>>4)*8 + e]
    short8 qf[2][2];
    {
        const float* qr = q + ((size_t)bh * MM + m0 + lo) * DD + hi * 8;
#pragma unroll
        for (int ks = 0; ks < 2; ++ks) {
            float4 a = *(const float4*)(qr + ks * 32);
            float4 b = *(const float4*)(qr + ks * 32 + 4);
            float f[8] = {a.x, a.y, a.z, a.w, b.x, b.y, b.z, b.w};
            short8 qh, ql;
#pragma unroll
            for (int e = 0; e < 8; ++e) {
                ushort_t hh = f2bf(f[e]);
                qh[e] = (short)hh;
                ql[e] = (short)f2bf(f[e] - bf2f(hh));
            }
            qf[ks][0] = qh;
            qf[ks][1] = ql;
        }
    }

    const ushort_t* KVb = wsKV + (size_t)h * (16 * 16384);

    auto STAGE = [&](int b, int c) {
        const char* src = (const char*)(KVb + (size_t)c * 16384) + w * 8192 + l * 16;
        char* dst = (char*)&kvbuf[b][0] + w * 8192;
#pragma unroll
        for (int j = 0; j < 8; ++j)
            __builtin_amdgcn_global_load_lds(
                (const __attribute__((address_space(1))) void*)(src + j * 1024),
                (__attribute__((address_space(3))) void*)(dst + j * 1024),
                16, 0, 0);
    };

    f32x4 oacc[4] = {{0.f,0.f,0.f,0.f},{0.f,0.f,0.f,0.f},{0.f,0.f,0.f,0.f},{0.f,0.f,0.f,0.f}};
    float m_run = -INFINITY, s_run = 0.f;

    STAGE(0, 0);
    __syncthreads();

    for (int c = 0; c < 16; ++c) {
        const int cur = c & 1;
        if (c < 15) STAGE(cur ^ 1, c + 1);

        const ushort_t* Kc = &kvbuf[cur][0];
        const ushort_t* Vc = Kc + 8192;

        // ---- S^T chunk: D[p][m], p = c*64 + pb*16 + hi*4 + reg, m = lo ----
        f32x4 sacc[4] = {{0.f,0.f,0.f,0.f},{0.f,0.f,0.f,0.f},{0.f,0.f,0.f,0.f},{0.f,0.f,0.f,0.f}};
        __builtin_amdgcn_s_setprio(1);
#pragma unroll
        for (int pb = 0; pb < 4; ++pb) {
#pragma unroll
            for (int ks = 0; ks < 2; ++ks) {
                const ushort_t* fp = Kc + (pb * 2 + ks) * 1024 + l * 8;
                short8 khi = *(const short8*)fp;
                short8 klo = *(const short8*)(fp + 512);
                sacc[pb] = MFMA(khi, qf[ks][0], sacc[pb]);
                sacc[pb] = MFMA(khi, qf[ks][1], sacc[pb]);
                sacc[pb] = MFMA(klo, qf[ks][0], sacc[pb]);
            }
        }
        __builtin_amdgcn_s_setprio(0);

        // ---- online softmax over the 64-p chunk (per m = lo, replicated over hi) ----
        float cm = -INFINITY;
#pragma unroll
        for (int pb = 0; pb < 4; ++pb)
#pragma unroll
            for (int r = 0; r < 4; ++r) cm = fmaxf(cm, sacc[pb][r]);
        cm = fmaxf(cm, __shfl_xor(cm, 16));
        cm = fmaxf(cm, __shfl_xor(cm, 32));
        float mnew = fmaxf(m_run, cm);

        float ep[4][4];
        float csum = 0.f;
#pragma unroll
        for (int pb = 0; pb < 4; ++pb)
#pragma unroll
            for (int r = 0; r < 4; ++r) {
                float e = __expf(sacc[pb][r] - mnew);
                ep[pb][r] = e;
                csum += e;
            }
        csum += __shfl_xor(csum, 16);
        csum += __shfl_xor(csum, 32);

        if (__all(cm <= m_run)) {
            s_run += csum;
        } else {
            float fac = __expf(m_run - mnew);   // first chunk: exp(-inf)=0
            s_run = s_run * fac + csum;
            m_run = mnew;
            float fr[4];
#pragma unroll
            for (int r = 0; r < 4; ++r) fr[r] = __shfl(fac, hi * 4 + r);
#pragma unroll
            for (int db = 0; db < 4; ++db)
#pragma unroll
                for (int r = 0; r < 4; ++r) oacc[db][r] *= fr[r];
        }

        // ---- P frags (A-operand, zero shuffles) + PV ----
#pragma unroll
        for (int ks2 = 0; ks2 < 2; ++ks2) {
            short8 phi8, plo8;
#pragma unroll
            for (int e = 0; e < 8; ++e) {
                float pv = ep[ks2 * 2 + (e >> 2)][e & 3];
                ushort_t hh = f2bf(pv);
                phi8[e] = (short)hh;
                plo8[e] = (short)f2bf(pv - bf2f(hh));
            }
            __builtin_amdgcn_s_setprio(1);
#pragma unroll
            for (int db = 0; db < 4; ++db) {
                const ushort_t* vp = Vc + (ks2 * 4 + db) * 1024 + l * 8;
                short8 vhi = *(const short8*)vp;
                short8 vlo = *(const short8*)(vp + 512);
                oacc[db] = MFMA(phi8, vhi, oacc[db]);
                oacc[db] = MFMA(plo8, vhi, oacc[db]);
                oacc[db] = MFMA(phi8, vlo, oacc[db]);
            }
            __builtin_amdgcn_s_setprio(0);
        }

        __syncthreads();   // buf[cur^1] staged; all waves done reading buf[cur]
    }

    // ---- epilogue: write per-row (m_pers, s_pers) + unscaled oacc (f16) ----
    if (hi == 0) {
        size_t row = (size_t)bh * MM + m0 + lo;
        ws_ms[row * 2]     = m_run;
        ws_ms[row * 2 + 1] = s_run;
    }
#pragma unroll
    for (int reg = 0; reg < 4; ++reg) {
        size_t ro = ((size_t)bh * MM + m0 + hi * 4 + reg) * DD + lo;
#pragma unroll
        for (int db = 0; db < 4; ++db)
            oraw[ro + db * 16] = (_Float16)oacc[db][reg];
    }
}

// ---------------- norm kernel: one wave per row; attn read ONCE ----------------
// Computes row stats in registers, merges pers stats, writes attn_out and out.
__launch_bounds__(256)
__global__ void pm_norm(const float* __restrict__ attn,
                        const float* __restrict__ ws_ms,
                        const _Float16* __restrict__ oraw,
                        float* __restrict__ attn_out,
                        float* __restrict__ out)
{
    const int t = threadIdx.x;
    const int w = t >> 6;
    const int l = t & 63;
    const size_t row = (size_t)blockIdx.x * 4 + w;   // 0..32767

    const float2 ms = ((const float2*)ws_ms)[row];   // (m_pers, s_pers)

    const f32x4* arow = (const f32x4*)(attn + row * SPAN);
    f32x4 av[4];
#pragma unroll
    for (int j = 0; j < 4; ++j) av[j] = __builtin_nontemporal_load(arow + j * 64 + l);

    float mx = -INFINITY;
#pragma unroll
    for (int j = 0; j < 4; ++j) {
        av[j] *= 0.125f;
        mx = fmaxf(mx, fmaxf(fmaxf(av[j][0], av[j][1]), fmaxf(av[j][2], av[j][3])));
    }
#pragma unroll
    for (int s = 1; s < 64; s <<= 1) mx = fmaxf(mx, __shfl_xor(mx, s));

    const float M = fmaxf(mx, ms.x);
    float sm = 0.f;
#pragma unroll
    for (int j = 0; j < 4; ++j)
#pragma unroll
        for (int e = 0; e < 4; ++e) {
            av[j][e] = __expf(av[j][e] - M);
            sm += av[j][e];
        }
#pragma unroll
    for (int s = 1; s < 64; s <<= 1) sm += __shfl_xor(sm, s);

    const float pfac = __expf(ms.x - M);             // exp(m_pers - M)
    const float Z  = sm + ms.y * pfac;
    const float iZ = 1.f / Z;

    f32x4* orow = (f32x4*)(attn_out + row * SPAN);
#pragma unroll
    for (int j = 0; j < 4; ++j)
        __builtin_nontemporal_store(av[j] * iZ, orow + j * 64 + l);

    // out row: 64 floats, lane l owns element l
    float ov = (float)oraw[row * DD + l];
    __builtin_nontemporal_store(ov * 32.f * pfac * iZ, &out[row * DD + l]);
}

// ---------------- fallback (fp32 VALU) if ws too small ----------------
__launch_bounds__(256)
__global__ void pm_fallback(const float* __restrict__ q,
                            const float* __restrict__ attn,
                            const float* __restrict__ key,
                            const float* __restrict__ val,
                            float* __restrict__ attn_out,
                            float* __restrict__ out)
{
    __shared__ float qs[64][68];
    __shared__ float ks[64][68];
    __shared__ float vs[64][DD];
    __shared__ float sc[64][66];
    __shared__ float rmax[64];
    __shared__ float rsum[64];

    const int t    = threadIdx.x;
    const int bh   = blockIdx.y;
    const int tile = blockIdx.x;
    const int h    = bh & (NH - 1);
    const int m0   = tile * 64;
    const int tr   = t >> 4;
    const int tc   = t & 15;
    const int r0   = tr * 4;
    const int c0   = tc * 4;
    const int lane = t & 63;
    const int wave = t >> 6;

    const size_t qbase = (size_t)bh * MM * DD + (size_t)m0 * DD;
    const size_t abase = (size_t)bh * MM * SPAN + (size_t)m0 * SPAN;
    const size_t kbase = (size_t)h * DD * PP;
    const size_t vbase = (size_t)h * PP * DD;

#pragma unroll
    for (int j = 0; j < 16; ++j) {
        int idx = j * 256 + t;
        int r = idx >> 6, d = idx & 63;
        qs[r][d] = q[qbase + (size_t)r * DD + d];
    }
    for (int rr = 0; rr < 16; ++rr) {
        int r = wave * 16 + rr;
        const float* arow = attn + abase + (size_t)r * SPAN;
        float av[16];
        float mx = -INFINITY;
#pragma unroll
        for (int j = 0; j < 16; ++j) { av[j] = arow[j * 64 + lane] * 0.125f; mx = fmaxf(mx, av[j]); }
#pragma unroll
        for (int s = 32; s; s >>= 1) mx = fmaxf(mx, __shfl_xor(mx, s));
        float sm = 0.f;
#pragma unroll
        for (int j = 0; j < 16; ++j) sm += __expf(av[j] - mx);
#pragma unroll
        for (int s = 32; s; s >>= 1) sm += __shfl_xor(sm, s);
        if (lane == 0) { rmax[r] = mx; rsum[r] = sm; }
    }
    __syncthreads();
    for (int p0 = 0; p0 < PP; p0 += 64) {
        if (p0) __syncthreads();
#pragma unroll
        for (int j = 0; j < 16; ++j) {
            int idx = j * 256 + t;
            int d = idx >> 6, pc = idx & 63;
            ks[pc][d] = key[kbase + (size_t)d * PP + p0 + pc];
        }
        __syncthreads();
        float acc[4][4] = {};
#pragma unroll
        for (int d0 = 0; d0 < DD; d0 += 4) {
            float4 q4[4], k4[4];
#pragma unroll
            for (int rr = 0; rr < 4; ++rr) q4[rr] = *(const float4*)&qs[r0 + rr][d0];
#pragma unroll
            for (int cc = 0; cc < 4; ++cc) k4[cc] = *(const float4*)&ks[c0 + cc][d0];
#pragma unroll
            for (int rr = 0; rr < 4; ++rr)
#pragma unroll
                for (int cc = 0; cc < 4; ++cc)
                    acc[rr][cc] += q4[rr].x * k4[cc].x + q4[rr].y * k4[cc].y
                                 + q4[rr].z * k4[cc].z + q4[rr].w * k4[cc].w;
        }
#pragma unroll
        for (int rr = 0; rr < 4; ++rr) {
            float mx = fmaxf(fmaxf(acc[rr][0], acc[rr][1]), fmaxf(acc[rr][2], acc[rr][3]));
#pragma unroll
            for (int s = 8; s; s >>= 1) mx = fmaxf(mx, __shfl_xor(mx, s));
            float sm = 0.f;
#pragma unroll
            for (int cc = 0; cc < 4; ++cc) sm += __expf(acc[rr][cc] - mx);
#pragma unroll
            for (int s = 8; s; s >>= 1) sm += __shfl_xor(sm, s);
            if (tc == 0) {
                int r = r0 + rr;
                float om = rmax[r], os = rsum[r];
                float nm = fmaxf(om, mx);
                rsum[r] = os * __expf(om - nm) + sm * __expf(mx - nm);
                rmax[r] = nm;
            }
        }
    }
    __syncthreads();
    for (int rr = 0; rr < 16; ++rr) {
        int r = wave * 16 + rr;
        float Mx = rmax[r];
        float iZ = 1.0f / rsum[r];
        const float* arow = attn + abase + (size_t)r * SPAN;
        float* orow = attn_out + abase + (size_t)r * SPAN;
#pragma unroll
        for (int j = 0; j < 16; ++j) {
            float a = arow[j * 64 + lane] * 0.125f;
            orow[j * 64 + lane] = __expf(a - Mx) * iZ;
        }
    }
    float acc2[4][4] = {};
    for (int p0 = 0; p0 < PP; p0 += 64) {
        __syncthreads();
#pragma unroll
        for (int j = 0; j < 16; ++j) {
            int idx = j * 256 + t;
            int d = idx >> 6, pc = idx & 63;
            ks[pc][d] = key[kbase + (size_t)d * PP + p0 + pc];
        }
#pragma unroll
        for (int j = 0; j < 16; ++j) {
            int idx = j * 256 + t;
            int pc = idx >> 6, d = idx & 63;
            vs[pc][d] = val[vbase + (size_t)(p0 + pc) * DD + d];
        }
        __syncthreads();
        float acc[4][4] = {};
#pragma unroll
        for (int d0 = 0; d0 < DD; d0 += 4) {
            float4 q4[4], k4[4];
#pragma unroll
            for (int rr = 0; rr < 4; ++rr) q4[rr] = *(const float4*)&qs[r0 + rr][d0];
#pragma unroll
            for (int cc = 0; cc < 4; ++cc) k4[cc] = *(const float4*)&ks[c0 + cc][d0];
#pragma unroll
            for (int rr = 0; rr < 4; ++rr)
#pragma unroll
                for (int cc = 0; cc < 4; ++cc)
                    acc[rr][cc] += q4[rr].x * k4[cc].x + q4[rr].y * k4[cc].y
                                 + q4[rr].z * k4[cc].z + q4[rr].w * k4[cc].w;
        }
#pragma unroll
        for (int rr = 0; rr < 4; ++rr) {
            float Mx = rmax[r0 + rr];
#pragma unroll
            for (int cc = 0; cc < 4; ++cc)
                sc[r0 + rr][c0 + cc] = __expf(acc[rr][cc] - Mx);
        }
        __syncthreads();
        for (int pc = 0; pc < 64; ++pc) {
            float4 v4 = *(const float4*)&vs[pc][tc * 4];
#pragma unroll
            for (int rr = 0; rr < 4; ++rr) {
                float pr = sc[r0 + rr][pc];
                acc2[rr][0] += pr * v4.x;
                acc2[rr][1] += pr * v4.y;
                acc2[rr][2] += pr * v4.z;
                acc2[rr][3] += pr * v4.w;
            }
        }
    }
#pragma unroll
    for (int rr = 0; rr < 4; ++rr) {
        int r = r0 + rr;
        float s = 32.0f / rsum[r];
        float4 o;
        o.x = acc2[rr][0] * s; o.y = acc2[rr][1] * s;
        o.z = acc2[rr][2] * s; o.w = acc2[rr][3] * s;
        *(float4*)&out[(size_t)bh * MM * DD + (size_t)(m0 + r) * DD + tc * 4] = o;
    }
}

extern "C" void kernel_launch(void* const* d_in, const int* in_sizes, int n_in,
                              void* d_out, int out_size, void* d_ws, size_t ws_size,
                              hipStream_t stream) {
    const float* q    = (const float*)d_in[0];
    const float* attn = (const float*)d_in[1];
    const float* key  = (const float*)d_in[2];
    const float* val  = (const float*)d_in[3];
    float* attn_out = (float*)d_out;
    float* out      = (float*)d_out + (size_t)BH * MM * SPAN;

    if (ws_size >= WS_NEED) {
        ushort_t*  wsKV  = (ushort_t*)d_ws;
        float*     ws_ms = (float*)((char*)d_ws + WS_MS_OFF);
        _Float16*  oraw  = (_Float16*)((char*)d_ws + WS_ORAW_OFF);
        pm_pre <<<1024, 256, 0, stream>>>(key, val, wsKV);
        pm_main<<<512, 256, 0, stream>>>(q, wsKV, ws_ms, oraw);
        pm_norm<<<8192, 256, 0, stream>>>(attn, ws_ms, oraw, attn_out, out);
    } else {
        dim3 grid(MM / 64, BH);
        pm_fallback<<<grid, 256, 0, stream>>>(q, attn, key, val, attn_out, out);
    }
}